// Round 7
// baseline (280.540 us; speedup 1.0000x reference)
//
#include <hip/hip_runtime.h>
#include <cstdint>
#include <math.h>

static constexpr int Bc = 2, Tc = 2048, Cch = 512, Hc = 8;
static constexpr int BT = Bc * Tc;          // 4096
static constexpr int NBH = Bc * Hc;         // 16
static constexpr int BANDS = 32;            // 64-row query bands per (b,h)
static constexpr size_t TRI_FLOATS = 2228224;  // causal-compact f32 per (b,h)

typedef float f32x4 __attribute__((ext_vector_type(4)));
typedef short s16x8 __attribute__((ext_vector_type(8)));
typedef unsigned short u16x8 __attribute__((ext_vector_type(8)));
typedef unsigned short u16x4 __attribute__((ext_vector_type(4)));

__device__ inline float wave_sum_f(float x) {
#pragma unroll
  for (int o = 32; o; o >>= 1) x += __shfl_xor(x, o);
  return x;
}
__device__ inline unsigned short f2bf(float x) {  // RNE f32->bf16 (finite)
  unsigned u = __float_as_uint(x);
  return (unsigned short)((u + 0x7FFFu + ((u >> 16) & 1u)) >> 16);
}
__device__ inline float bf2f(unsigned short h) { return __uint_as_float(((unsigned)h) << 16); }
__device__ inline float su2f(unsigned s) {  // inverse order-preserving map
  unsigned u = (s & 0x80000000u) ? (s ^ 0x80000000u) : ~s;
  return __uint_as_float(u);
}

// ---------- split f32 -> bf16 hi/lo ----------
__global__ __launch_bounds__(256) void split_k(const float* __restrict__ X,
    unsigned short* __restrict__ hi, unsigned short* __restrict__ lo, int n8) {
  int i = blockIdx.x * 256 + threadIdx.x;
  if (i >= n8) return;
  const f32x4* p = (const f32x4*)X + (size_t)i * 2;
  f32x4 a = p[0], b = p[1];
  float v[8] = {a[0], a[1], a[2], a[3], b[0], b[1], b[2], b[3]};
  u16x8 h, l;
#pragma unroll
  for (int c = 0; c < 8; c++) {
    unsigned short hh = f2bf(v[c]);
    h[c] = hh;
    l[c] = f2bf(v[c] - bf2f(hh));
  }
  *(u16x8*)(hi + (size_t)i * 8) = h;
  *(u16x8*)(lo + (size_t)i * 8) = l;
}

// ---------- split + transpose weights: W[k][n] f32 -> WT[n][k] bf16 hi/lo ----------
__global__ __launch_bounds__(256) void splitT_k(const float* __restrict__ W,
    unsigned short* __restrict__ hiT, unsigned short* __restrict__ loT) {
  __shared__ float t[64][65];
  const int tid = threadIdx.x;
  const int k0 = blockIdx.x * 64, n0 = blockIdx.y * 64;
#pragma unroll
  for (int p = 0; p < 4; p++) {
    int idx = tid + p * 256, kk = idx >> 4, n4 = idx & 15;
    f32x4 v = *(const f32x4*)&W[(size_t)(k0 + kk) * Cch + n0 + n4 * 4];
    t[kk][n4 * 4 + 0] = v[0]; t[kk][n4 * 4 + 1] = v[1];
    t[kk][n4 * 4 + 2] = v[2]; t[kk][n4 * 4 + 3] = v[3];
  }
  __syncthreads();
  {
    int n = tid >> 2, ks = tid & 3;
    u16x8 h0, h1, l0, l1;
#pragma unroll
    for (int kk = 0; kk < 8; kk++) {
      float x = t[ks * 16 + kk][n];
      unsigned short hh = f2bf(x);
      h0[kk] = hh; l0[kk] = f2bf(x - bf2f(hh));
      float y = t[ks * 16 + 8 + kk][n];
      unsigned short hy = f2bf(y);
      h1[kk] = hy; l1[kk] = f2bf(y - bf2f(hy));
    }
    size_t base = (size_t)(n0 + n) * Cch + k0 + ks * 16;
    *(u16x8*)(hiT + base) = h0; *(u16x8*)(hiT + base + 8) = h1;
    *(u16x8*)(loT + base) = l0; *(u16x8*)(loT + base + 8) = l1;
  }
}

// ---------- bf16x3 MFMA GEMM: Out[M=4096][512] = (Ahi+Alo)@(BT)^T + bias ----------
template <int BF16OUT>
__global__ __launch_bounds__(256) void gemm3_k(
    const unsigned short* __restrict__ Ahi, const unsigned short* __restrict__ Alo,
    const unsigned short* __restrict__ Bhi, const unsigned short* __restrict__ Blo,
    const float* __restrict__ bias, void* __restrict__ Out) {
  __shared__ unsigned short Ah[2][64][72];
  __shared__ unsigned short Bs[2][64][72];
  const int tid = threadIdx.x;
  const int w = tid >> 6, lane = tid & 63, e = lane >> 4, lr = lane & 15;
  const int wr = w >> 1, wc = w & 1;
  const int brow = blockIdx.y * 64, bcol = blockIdx.x * 64;
  f32x4 acc[2][2] = {};
  for (int k0 = 0; k0 < Cch; k0 += 64) {
#pragma unroll
    for (int p = 0; p < 2; p++) {
      int idx = tid + p * 256, row = idx >> 3, seg = idx & 7;
      *(u16x8*)&Ah[0][row][seg * 8] = *(const u16x8*)&Ahi[(size_t)(brow + row) * Cch + k0 + seg * 8];
      *(u16x8*)&Ah[1][row][seg * 8] = *(const u16x8*)&Alo[(size_t)(brow + row) * Cch + k0 + seg * 8];
      *(u16x8*)&Bs[0][row][seg * 8] = *(const u16x8*)&Bhi[(size_t)(bcol + row) * Cch + k0 + seg * 8];
      *(u16x8*)&Bs[1][row][seg * 8] = *(const u16x8*)&Blo[(size_t)(bcol + row) * Cch + k0 + seg * 8];
    }
    __syncthreads();
#pragma unroll
    for (int ks = 0; ks < 2; ks++) {
      s16x8 ah[2], al[2], bh[2], bl[2];
#pragma unroll
      for (int ti = 0; ti < 2; ti++) {
        ah[ti] = *(const s16x8*)&Ah[0][wr * 32 + ti * 16 + lr][ks * 32 + e * 8];
        al[ti] = *(const s16x8*)&Ah[1][wr * 32 + ti * 16 + lr][ks * 32 + e * 8];
      }
#pragma unroll
      for (int tj = 0; tj < 2; tj++) {
        bh[tj] = *(const s16x8*)&Bs[0][wc * 32 + tj * 16 + lr][ks * 32 + e * 8];
        bl[tj] = *(const s16x8*)&Bs[1][wc * 32 + tj * 16 + lr][ks * 32 + e * 8];
      }
#pragma unroll
      for (int ti = 0; ti < 2; ti++)
#pragma unroll
        for (int tj = 0; tj < 2; tj++) {
          acc[ti][tj] = __builtin_amdgcn_mfma_f32_16x16x32_bf16(ah[ti], bh[tj], acc[ti][tj], 0, 0, 0);
          acc[ti][tj] = __builtin_amdgcn_mfma_f32_16x16x32_bf16(ah[ti], bl[tj], acc[ti][tj], 0, 0, 0);
          acc[ti][tj] = __builtin_amdgcn_mfma_f32_16x16x32_bf16(al[ti], bh[tj], acc[ti][tj], 0, 0, 0);
        }
    }
    __syncthreads();
  }
#pragma unroll
  for (int ti = 0; ti < 2; ti++)
#pragma unroll
    for (int tj = 0; tj < 2; tj++) {
      int col = bcol + wc * 32 + tj * 16 + lr;
      float bi = bias[col];
#pragma unroll
      for (int r = 0; r < 4; r++) {
        int row = brow + wr * 32 + ti * 16 + e * 4 + r;
        float v = acc[ti][tj][r] + bi;
        if (BF16OUT) ((unsigned short*)Out)[(size_t)row * Cch + col] = f2bf(v);
        else         ((float*)Out)[(size_t)row * Cch + col] = v;
      }
    }
}

// ---------- V normalize + transpose via LDS: Vf[token][C] f32 -> Vt[bh*64+d][t] bf16 ----------
__global__ __launch_bounds__(256) void vnormt_k(const float* __restrict__ Vf,
                                                unsigned short* __restrict__ Vt) {
  __shared__ unsigned short T[64][72];  // [d][token] bf16
  const int tid = threadIdx.x;
  const int t0 = blockIdx.x * 64;
  const int h = blockIdx.y;
  const int tok = tid >> 2;
  const int q = tid & 3;
  const float* src = Vf + (size_t)(t0 + tok) * Cch + h * 64 + q * 16;
  f32x4 v[4];
  float ss = 0.f;
#pragma unroll
  for (int i = 0; i < 4; i++) {
    v[i] = *(const f32x4*)(src + i * 4);
#pragma unroll
    for (int c = 0; c < 4; c++) ss += v[i][c] * v[i][c];
  }
  ss += __shfl_xor(ss, 1);
  ss += __shfl_xor(ss, 2);
  float inv = 1.0f / fmaxf(sqrtf(ss), 1e-12f);
#pragma unroll
  for (int i = 0; i < 4; i++)
#pragma unroll
    for (int c = 0; c < 4; c++)
      T[q * 16 + i * 4 + c][tok] = f2bf(v[i][c] * inv);
  __syncthreads();
  const int d = tid >> 2, s2 = (tid & 3) * 2;
  const int b = t0 >> 11;
  size_t base = ((size_t)((b * Hc + h) * 64 + d)) * Tc + (t0 & 2047);
  *(u16x8*)(Vt + base + s2 * 8)     = *(const u16x8*)&T[d][s2 * 8];
  *(u16x8*)(Vt + base + s2 * 8 + 8) = *(const u16x8*)&T[d][s2 * 8 + 8];
}

// ---------- fused attention band kernel: QK^T -> exact top-64 softmax -> PV ----------
// block = (band of 64 query rows, bh); S scratch is written+read by the SAME CU (L2-hot)
__global__ __launch_bounds__(512, 4) void attn_band_k(
    const unsigned short* __restrict__ Qp, const unsigned short* __restrict__ Kp,
    const unsigned short* __restrict__ Vt, float* __restrict__ Sb,
    unsigned short* __restrict__ Yhi, unsigned short* __restrict__ Ylo, int bh0)
{
  __shared__ __align__(16) char smem[35072];
  unsigned short (*Qs)[72]  = (unsigned short(*)[72])(smem);           // 64x72  (phase A)
  unsigned short (*Ks)[72]  = (unsigned short(*)[72])(smem + 9216);    // 128x72 (phase A)
  unsigned short (*Ps)[136] = (unsigned short(*)[136])(smem);          // 64x136 (phase C)
  unsigned short (*Vs)[136] = (unsigned short(*)[136])(smem + 17408);  // 64x136 (phase C)
  float* invl = (float*)(smem + 34816);                                // 64 f32

  const int x = blockIdx.x;
  const int bb = (x & 1) ? (BANDS - 1 - (x >> 1)) : (x >> 1);  // pair big/small bands per CU
  const int bh = bh0 + blockIdx.y, b = bh >> 3, h = bh & 7;
  const int p = bb >> 1;
  const int stride = (p + 1) * 128;     // padded causal row length for this band
  const int nkt = p + 1;                // 128-key tiles
  float* band = Sb + (size_t)(bh - bh0) * TRI_FLOATS
              + (size_t)8192 * (size_t)(p + 1) * (size_t)(p + (bb & 1));
  const int tid = threadIdx.x, w = tid >> 6, lane = tid & 63, e = lane >> 4, lr = lane & 15;
  const int row0 = bb * 64;

  // ---- phase A: S = (Q K^T)/8 for the whole band ----
  {
    int qr = tid >> 3, seg = tid & 7;
    *(u16x8*)&Qs[qr][seg * 8] =
        *(const u16x8*)&Qp[((size_t)(b * Tc + row0 + qr)) * Cch + h * 64 + seg * 8];
  }
  __syncthreads();
  s16x8 qa[4][2];
#pragma unroll
  for (int ti = 0; ti < 4; ti++)
#pragma unroll
    for (int ks = 0; ks < 2; ks++)
      qa[ti][ks] = *(const s16x8*)&Qs[ti * 16 + lr][ks * 32 + e * 8];

  for (int kt = 0; kt < nkt; kt++) {
#pragma unroll
    for (int pp = 0; pp < 2; pp++) {
      int idx = tid + pp * 512, kr = idx >> 3, seg = idx & 7;
      *(u16x8*)&Ks[kr][seg * 8] =
          *(const u16x8*)&Kp[((size_t)(b * Tc + kt * 128 + kr)) * Cch + h * 64 + seg * 8];
    }
    __syncthreads();
    f32x4 acc[4] = {};
#pragma unroll
    for (int ks = 0; ks < 2; ks++) {
      s16x8 kb = *(const s16x8*)&Ks[w * 16 + lr][ks * 32 + e * 8];
#pragma unroll
      for (int ti = 0; ti < 4; ti++)
        acc[ti] = __builtin_amdgcn_mfma_f32_16x16x32_bf16(qa[ti][ks], kb, acc[ti], 0, 0, 0);
    }
#pragma unroll
    for (int ti = 0; ti < 4; ti++)
#pragma unroll
      for (int r2 = 0; r2 < 4; r2++)
        band[(size_t)(ti * 16 + e * 4 + r2) * stride + kt * 128 + w * 16 + lr] = acc[ti][r2] * 0.125f;
    __syncthreads();
  }

  // ---- phase B: exact top-64 + softmax per row (8 rows per wave, serial) ----
#pragma unroll 1
  for (int rr = 0; rr < 8; rr++) {
    const int lrow = w * 8 + rr;
    const int t = row0 + lrow;
    float* row = band + (size_t)lrow * stride;
    unsigned su[32];
#pragma unroll
    for (int c = 0; c < 8; c++) {
      if (c * 256 < stride) {
        int j0 = c * 256 + lane * 4;
        f32x4 v;
        if (j0 < stride) v = *(const f32x4*)(row + j0);
        else { v[0] = v[1] = v[2] = v[3] = -INFINITY; }
#pragma unroll
        for (int cc = 0; cc < 4; cc++) {
          float xv = (j0 + cc <= t) ? v[cc] : -INFINITY;
          unsigned u = __float_as_uint(xv);
          su[c * 4 + cc] = (u & 0x80000000u) ? ~u : (u | 0x80000000u);
        }
      } else {
#pragma unroll
        for (int cc = 0; cc < 4; cc++) su[c * 4 + cc] = 0x007FFFFFu;  // map(-inf)
      }
    }
    unsigned lo = 0;
#pragma unroll 1
    for (int bit = 31; bit >= 0; bit--) {
      unsigned cand = lo | (1u << bit);
      int cnt = 0;
#pragma unroll
      for (int c = 0; c < 8; c++)
        if (c * 256 < stride)
#pragma unroll
          for (int q = 0; q < 4; q++)
            cnt += (int)__popcll(__ballot(su[c * 4 + q] >= cand));
      if (cnt >= 64) {
        lo = cand;
        if (cnt == 64) {
          unsigned mn = 0xFFFFFFFFu;
#pragma unroll
          for (int c = 0; c < 8; c++)
            if (c * 256 < stride)
#pragma unroll
              for (int q = 0; q < 4; q++) { unsigned xv = (su[c * 4 + q] >= cand) ? su[c * 4 + q] : 0xFFFFFFFFu; mn = mn < xv ? mn : xv; }
#pragma unroll
          for (int o = 32; o; o >>= 1) { unsigned xv = (unsigned)__shfl_xor((int)mn, o); mn = mn < xv ? mn : xv; }
          lo = mn;
          break;
        }
      }
    }
    unsigned mx = 0;
#pragma unroll
    for (int c = 0; c < 8; c++)
      if (c * 256 < stride)
#pragma unroll
        for (int q = 0; q < 4; q++) mx = mx > su[c * 4 + q] ? mx : su[c * 4 + q];
#pragma unroll
    for (int o = 32; o; o >>= 1) { unsigned xv = (unsigned)__shfl_xor((int)mx, o); mx = mx > xv ? mx : xv; }
    float m = su2f(mx);
    float sum = 0.f;
#pragma unroll
    for (int c = 0; c < 8; c++)
      if (c * 256 < stride)
#pragma unroll
        for (int q = 0; q < 4; q++) {
          float v = su2f(su[c * 4 + q]);
          float wv = (su[c * 4 + q] >= lo) ? __expf(v - m) : 0.f;  // exp(-inf)=0
          su[c * 4 + q] = __float_as_uint(wv);
          sum += wv;
        }
    sum = wave_sum_f(sum);
    if (lane == 0) invl[lrow] = 1.f / sum;
    unsigned short* prow = (unsigned short*)row;
#pragma unroll
    for (int c = 0; c < 8; c++) {
      if (c * 256 < stride) {
        int j0 = c * 256 + lane * 4;
        if (j0 < stride) {
          u16x4 pk;
#pragma unroll
          for (int cc = 0; cc < 4; cc++) pk[cc] = f2bf(__uint_as_float(su[c * 4 + cc]));
          *(u16x4*)(prow + j0) = pk;
        }
      }
    }
  }
  __syncthreads();

  // ---- phase C: Y = P @ V^T, scale by invl in epilogue ----
  const int ci = w & 3;
  const int rg = (w >> 2) * 2;
  f32x4 accp[2] = {};
  for (int kt = 0; kt < nkt; kt++) {
#pragma unroll
    for (int pp = 0; pp < 2; pp++) {
      int idx = tid + pp * 512, pr = idx >> 4, seg = idx & 15;
      *(u16x8*)&Ps[pr][seg * 8] =
          *(const u16x8*)&((const unsigned short*)(band + (size_t)pr * stride))[kt * 128 + seg * 8];
      int d = pr;
      *(u16x8*)&Vs[d][seg * 8] =
          *(const u16x8*)&Vt[((size_t)(bh * 64 + d)) * Tc + kt * 128 + seg * 8];
    }
    __syncthreads();
#pragma unroll
    for (int ks = 0; ks < 4; ks++) {
      s16x8 bv = *(const s16x8*)&Vs[ci * 16 + lr][ks * 32 + e * 8];
#pragma unroll
      for (int tt = 0; tt < 2; tt++) {
        s16x8 a = *(const s16x8*)&Ps[(rg + tt) * 16 + lr][ks * 32 + e * 8];
        accp[tt] = __builtin_amdgcn_mfma_f32_16x16x32_bf16(a, bv, accp[tt], 0, 0, 0);
      }
    }
    __syncthreads();
  }
#pragma unroll
  for (int tt = 0; tt < 2; tt++)
#pragma unroll
    for (int r2 = 0; r2 < 4; r2++) {
      int lrow = (rg + tt) * 16 + e * 4 + r2;
      float y = accp[tt][r2] * invl[lrow];
      size_t g = ((size_t)(b * Tc + row0 + lrow)) * Cch + h * 64 + ci * 16 + lr;
      unsigned short hh = f2bf(y);
      Yhi[g] = hh;
      Ylo[g] = f2bf(y - bf2f(hh));
    }
}

extern "C" void kernel_launch(void* const* d_in, const int* in_sizes, int n_in,
                              void* d_out, int out_size, void* d_ws, size_t ws_size,
                              hipStream_t stream) {
  const float* q  = (const float*)d_in[0];
  // d_in[1] = tgt_mask: pure causal tril, handled analytically
  const float* Wq = (const float*)d_in[2];
  const float* bq = (const float*)d_in[3];
  const float* Wk = (const float*)d_in[4];
  const float* bk = (const float*)d_in[5];
  const float* Wv = (const float*)d_in[6];
  const float* bv = (const float*)d_in[7];
  const float* Wp = (const float*)d_in[8];
  const float* bp = (const float*)d_in[9];
  float* out = (float*)d_out;
  char* ws = (char*)d_ws;
  constexpr size_t MB = 1u << 20;

  unsigned short* qhi = (unsigned short*)(ws + 0 * MB);   // 4 MB (later Yhi)
  unsigned short* qlo = (unsigned short*)(ws + 4 * MB);   // 4 MB (later Ylo)
  unsigned short* Qp  = (unsigned short*)(ws + 8 * MB);   // 4 MB
  unsigned short* Kp  = (unsigned short*)(ws + 12 * MB);  // 4 MB
  unsigned short* Vt  = (unsigned short*)(ws + 16 * MB);  // 4 MB
  unsigned short* wsp = (unsigned short*)(ws + 20 * MB);  // 8 x 512 KB weight splits
  float* Sb = (float*)(ws + 24 * MB);                     // S/P scratch (chunked)
  float* Vf = (float*)(ws + 24 * MB);                     // overlays S (consumed first)
  unsigned short* Yhi = qhi;
  unsigned short* Ylo = qlo;
  auto WT = [&](int i) { return wsp + (size_t)i * 262144; };

  int nbh = NBH;
  while (nbh > 1 && 24 * MB + TRI_FLOATS * 4 * (size_t)nbh > ws_size) nbh >>= 1;

  split_k<<<(BT * Cch / 8 + 255) / 256, 256, 0, stream>>>(q, qhi, qlo, BT * Cch / 8);
  dim3 g8(8, 8);
  splitT_k<<<g8, 256, 0, stream>>>(Wq, WT(0), WT(1));
  splitT_k<<<g8, 256, 0, stream>>>(Wk, WT(2), WT(3));
  splitT_k<<<g8, 256, 0, stream>>>(Wv, WT(4), WT(5));
  splitT_k<<<g8, 256, 0, stream>>>(Wp, WT(6), WT(7));

  dim3 gp(Cch / 64, BT / 64);  // (8, 64)
  gemm3_k<1><<<gp, 256, 0, stream>>>(qhi, qlo, WT(0), WT(1), bq, Qp);
  gemm3_k<1><<<gp, 256, 0, stream>>>(qhi, qlo, WT(2), WT(3), bk, Kp);
  gemm3_k<0><<<gp, 256, 0, stream>>>(qhi, qlo, WT(4), WT(5), bv, Vf);
  vnormt_k<<<dim3(BT / 64, Hc), 256, 0, stream>>>(Vf, Vt);

  for (int c = 0; c < NBH / nbh; c++) {
    int bh0 = c * nbh;
    attn_band_k<<<dim3(BANDS, nbh), 512, 0, stream>>>(Qp, Kp, Vt, Sb, Yhi, Ylo, bh0);
  }

  gemm3_k<0><<<gp, 256, 0, stream>>>(Yhi, Ylo, WT(6), WT(7), bp, out);
}

// Round 8
// 226.421 us; speedup vs baseline: 1.2390x; 1.2390x over previous
//
#include <hip/hip_runtime.h>
#include <cstdint>
#include <math.h>

static constexpr int Bc = 2, Tc = 2048, Cch = 512, Hc = 8;
static constexpr int BT = Bc * Tc;          // 4096
static constexpr int NBH = Bc * Hc;         // 16
static constexpr int NRT = Tc / 128;        // 16 row-tiles per (b,h)
static constexpr int NTRI = NRT * (NRT + 1) / 2;  // 136 causal blocks
static constexpr size_t TRI_FLOATS = (size_t)NTRI * 16384;  // f32 per (b,h)

typedef float f32x4 __attribute__((ext_vector_type(4)));
typedef short s16x8 __attribute__((ext_vector_type(8)));
typedef unsigned short u16x8 __attribute__((ext_vector_type(8)));
typedef unsigned short u16x4 __attribute__((ext_vector_type(4)));

__device__ __host__ inline constexpr int tri_i(int r) { return r * (r + 1) / 2; }

__device__ inline float wave_sum_f(float x) {
#pragma unroll
  for (int o = 32; o; o >>= 1) x += __shfl_xor(x, o);
  return x;
}
__device__ inline unsigned short f2bf(float x) {  // RNE f32->bf16 (finite)
  unsigned u = __float_as_uint(x);
  return (unsigned short)((u + 0x7FFFu + ((u >> 16) & 1u)) >> 16);
}
__device__ inline float bf2f(unsigned short h) { return __uint_as_float(((unsigned)h) << 16); }
__device__ inline float su2f(unsigned s) {  // inverse order-preserving map
  unsigned u = (s & 0x80000000u) ? (s ^ 0x80000000u) : ~s;
  return __uint_as_float(u);
}

// ---------- split f32 -> bf16 hi/lo ----------
__global__ __launch_bounds__(256) void split_k(const float* __restrict__ X,
    unsigned short* __restrict__ hi, unsigned short* __restrict__ lo, int n8) {
  int i = blockIdx.x * 256 + threadIdx.x;
  if (i >= n8) return;
  const f32x4* p = (const f32x4*)X + (size_t)i * 2;
  f32x4 a = p[0], b = p[1];
  float v[8] = {a[0], a[1], a[2], a[3], b[0], b[1], b[2], b[3]};
  u16x8 h, l;
#pragma unroll
  for (int c = 0; c < 8; c++) {
    unsigned short hh = f2bf(v[c]);
    h[c] = hh;
    l[c] = f2bf(v[c] - bf2f(hh));
  }
  *(u16x8*)(hi + (size_t)i * 8) = h;
  *(u16x8*)(lo + (size_t)i * 8) = l;
}

// ---------- split + transpose weights: W[k][n] f32 -> WT[n][k] bf16 hi/lo ----------
__global__ __launch_bounds__(256) void splitT_k(const float* __restrict__ W,
    unsigned short* __restrict__ hiT, unsigned short* __restrict__ loT) {
  __shared__ float t[64][65];
  const int tid = threadIdx.x;
  const int k0 = blockIdx.x * 64, n0 = blockIdx.y * 64;
#pragma unroll
  for (int p = 0; p < 4; p++) {
    int idx = tid + p * 256, kk = idx >> 4, n4 = idx & 15;
    f32x4 v = *(const f32x4*)&W[(size_t)(k0 + kk) * Cch + n0 + n4 * 4];
    t[kk][n4 * 4 + 0] = v[0]; t[kk][n4 * 4 + 1] = v[1];
    t[kk][n4 * 4 + 2] = v[2]; t[kk][n4 * 4 + 3] = v[3];
  }
  __syncthreads();
  {
    int n = tid >> 2, ks = tid & 3;
    u16x8 h0, h1, l0, l1;
#pragma unroll
    for (int kk = 0; kk < 8; kk++) {
      float x = t[ks * 16 + kk][n];
      unsigned short hh = f2bf(x);
      h0[kk] = hh; l0[kk] = f2bf(x - bf2f(hh));
      float y = t[ks * 16 + 8 + kk][n];
      unsigned short hy = f2bf(y);
      h1[kk] = hy; l1[kk] = f2bf(y - bf2f(hy));
    }
    size_t base = (size_t)(n0 + n) * Cch + k0 + ks * 16;
    *(u16x8*)(hiT + base) = h0; *(u16x8*)(hiT + base + 8) = h1;
    *(u16x8*)(loT + base) = l0; *(u16x8*)(loT + base + 8) = l1;
  }
}

// ---------- bf16x3 MFMA GEMM: Out[M=4096][512] = (Ahi+Alo)@(BT)^T + bias ----------
template <int BF16OUT>
__global__ __launch_bounds__(256) void gemm3_k(
    const unsigned short* __restrict__ Ahi, const unsigned short* __restrict__ Alo,
    const unsigned short* __restrict__ Bhi, const unsigned short* __restrict__ Blo,
    const float* __restrict__ bias, void* __restrict__ Out) {
  __shared__ unsigned short Ah[2][64][72];
  __shared__ unsigned short Bs[2][64][72];
  const int tid = threadIdx.x;
  const int w = tid >> 6, lane = tid & 63, e = lane >> 4, lr = lane & 15;
  const int wr = w >> 1, wc = w & 1;
  const int brow = blockIdx.y * 64, bcol = blockIdx.x * 64;
  f32x4 acc[2][2] = {};
  for (int k0 = 0; k0 < Cch; k0 += 64) {
#pragma unroll
    for (int p = 0; p < 2; p++) {
      int idx = tid + p * 256, row = idx >> 3, seg = idx & 7;
      *(u16x8*)&Ah[0][row][seg * 8] = *(const u16x8*)&Ahi[(size_t)(brow + row) * Cch + k0 + seg * 8];
      *(u16x8*)&Ah[1][row][seg * 8] = *(const u16x8*)&Alo[(size_t)(brow + row) * Cch + k0 + seg * 8];
      *(u16x8*)&Bs[0][row][seg * 8] = *(const u16x8*)&Bhi[(size_t)(bcol + row) * Cch + k0 + seg * 8];
      *(u16x8*)&Bs[1][row][seg * 8] = *(const u16x8*)&Blo[(size_t)(bcol + row) * Cch + k0 + seg * 8];
    }
    __syncthreads();
#pragma unroll
    for (int ks = 0; ks < 2; ks++) {
      s16x8 ah[2], al[2], bh[2], bl[2];
#pragma unroll
      for (int ti = 0; ti < 2; ti++) {
        ah[ti] = *(const s16x8*)&Ah[0][wr * 32 + ti * 16 + lr][ks * 32 + e * 8];
        al[ti] = *(const s16x8*)&Ah[1][wr * 32 + ti * 16 + lr][ks * 32 + e * 8];
      }
#pragma unroll
      for (int tj = 0; tj < 2; tj++) {
        bh[tj] = *(const s16x8*)&Bs[0][wc * 32 + tj * 16 + lr][ks * 32 + e * 8];
        bl[tj] = *(const s16x8*)&Bs[1][wc * 32 + tj * 16 + lr][ks * 32 + e * 8];
      }
#pragma unroll
      for (int ti = 0; ti < 2; ti++)
#pragma unroll
        for (int tj = 0; tj < 2; tj++) {
          acc[ti][tj] = __builtin_amdgcn_mfma_f32_16x16x32_bf16(ah[ti], bh[tj], acc[ti][tj], 0, 0, 0);
          acc[ti][tj] = __builtin_amdgcn_mfma_f32_16x16x32_bf16(ah[ti], bl[tj], acc[ti][tj], 0, 0, 0);
          acc[ti][tj] = __builtin_amdgcn_mfma_f32_16x16x32_bf16(al[ti], bh[tj], acc[ti][tj], 0, 0, 0);
        }
    }
    __syncthreads();
  }
#pragma unroll
  for (int ti = 0; ti < 2; ti++)
#pragma unroll
    for (int tj = 0; tj < 2; tj++) {
      int col = bcol + wc * 32 + tj * 16 + lr;
      float bi = bias[col];
#pragma unroll
      for (int r = 0; r < 4; r++) {
        int row = brow + wr * 32 + ti * 16 + e * 4 + r;
        float v = acc[ti][tj][r] + bi;
        if (BF16OUT) ((unsigned short*)Out)[(size_t)row * Cch + col] = f2bf(v);
        else         ((float*)Out)[(size_t)row * Cch + col] = v;
      }
    }
}

// ---------- V normalize + transpose via LDS: Vf[token][C] f32 -> Vt[bh*64+d][t] bf16 ----------
__global__ __launch_bounds__(256) void vnormt_k(const float* __restrict__ Vf,
                                                unsigned short* __restrict__ Vt) {
  __shared__ unsigned short T[64][72];  // [d][token] bf16
  const int tid = threadIdx.x;
  const int t0 = blockIdx.x * 64;
  const int h = blockIdx.y;
  const int tok = tid >> 2;
  const int q = tid & 3;
  const float* src = Vf + (size_t)(t0 + tok) * Cch + h * 64 + q * 16;
  f32x4 v[4];
  float ss = 0.f;
#pragma unroll
  for (int i = 0; i < 4; i++) {
    v[i] = *(const f32x4*)(src + i * 4);
#pragma unroll
    for (int c = 0; c < 4; c++) ss += v[i][c] * v[i][c];
  }
  ss += __shfl_xor(ss, 1);
  ss += __shfl_xor(ss, 2);
  float inv = 1.0f / fmaxf(sqrtf(ss), 1e-12f);
#pragma unroll
  for (int i = 0; i < 4; i++)
#pragma unroll
    for (int c = 0; c < 4; c++)
      T[q * 16 + i * 4 + c][tok] = f2bf(v[i][c] * inv);
  __syncthreads();
  const int d = tid >> 2, s2 = (tid & 3) * 2;
  const int b = t0 >> 11;
  size_t base = ((size_t)((b * Hc + h) * 64 + d)) * Tc + (t0 & 2047);
  *(u16x8*)(Vt + base + s2 * 8)     = *(const u16x8*)&T[d][s2 * 8];
  *(u16x8*)(Vt + base + s2 * 8 + 8) = *(const u16x8*)&T[d][s2 * 8 + 8];
}

// ---------- S = (Q K^T)/8 into causal-compact triangular storage ----------
__global__ __launch_bounds__(512) void sqk_k(const unsigned short* __restrict__ Qp,
    const unsigned short* __restrict__ Kp, float* __restrict__ S, int bh0) {
  __shared__ unsigned short Qs[128][72], Ks[128][72];
  int rt, ct;
  {
    int i = blockIdx.x;
    int r = (int)((sqrtf(8.f * i + 1.f) - 1.f) * 0.5f);
    while ((r + 1) * (r + 2) / 2 <= i) r++;
    while (r * (r + 1) / 2 > i) r--;
    rt = r; ct = i - r * (r + 1) / 2;
  }
  const int bh = bh0 + blockIdx.y, b = bh >> 3, h = bh & 7;
  const int tid = threadIdx.x, w = tid >> 6, lane = tid & 63, e = lane >> 4, lr = lane & 15;
#pragma unroll
  for (int p = 0; p < 2; p++) {
    int idx = tid + p * 512, row = idx >> 3, seg = idx & 7;
    *(u16x8*)&Qs[row][seg * 8] = *(const u16x8*)&Qp[((size_t)(b * Tc + rt * 128 + row)) * Cch + h * 64 + seg * 8];
    *(u16x8*)&Ks[row][seg * 8] = *(const u16x8*)&Kp[((size_t)(b * Tc + ct * 128 + row)) * Cch + h * 64 + seg * 8];
  }
  __syncthreads();
  f32x4 acc[8] = {};
  s16x8 a[2];
#pragma unroll
  for (int ks = 0; ks < 2; ks++) a[ks] = *(const s16x8*)&Qs[w * 16 + lr][ks * 32 + e * 8];
#pragma unroll
  for (int tj = 0; tj < 8; tj++) {
#pragma unroll
    for (int ks = 0; ks < 2; ks++) {
      s16x8 bb = *(const s16x8*)&Ks[tj * 16 + lr][ks * 32 + e * 8];
      acc[tj] = __builtin_amdgcn_mfma_f32_16x16x32_bf16(a[ks], bb, acc[tj], 0, 0, 0);
    }
  }
  float* Srow0 = S + (size_t)(bh - bh0) * TRI_FLOATS + (size_t)tri_i(rt) * 16384;
  const int stride = (rt + 1) * 128;
#pragma unroll
  for (int tj = 0; tj < 8; tj++)
#pragma unroll
    for (int r = 0; r < 4; r++) {
      int row = w * 16 + e * 4 + r;
      Srow0[(size_t)row * stride + ct * 128 + tj * 16 + lr] = acc[tj][r] * 0.125f;
    }
}

// ---------- exact top-64 + softmax; writes normalized P bf16 in-place ----------
// chunk-guarded; launch_bounds(512,4) so su[32] stays in VGPRs (24-reg spill fix)
__global__ __launch_bounds__(512, 4) void sel_k(float* __restrict__ S) {
  int wid = blockIdx.x * 8 + (threadIdx.x >> 6);
  int lane = threadIdx.x & 63;
  int bhl = wid >> 11, t = wid & 2047;
  int rt = t >> 7, lrow = t & 127;
  int stride = (rt + 1) * 128;
  float* row = S + (size_t)bhl * TRI_FLOATS + (size_t)tri_i(rt) * 16384 + (size_t)lrow * stride;
  unsigned su[32];
#pragma unroll
  for (int c = 0; c < 8; c++) {
    if (c * 256 < stride) {
      int j0 = c * 256 + lane * 4;
      f32x4 v;
      if (j0 < stride) v = *(const f32x4*)(row + j0);
      else { v[0] = v[1] = v[2] = v[3] = -INFINITY; }
#pragma unroll
      for (int cc = 0; cc < 4; cc++) {
        float x = (j0 + cc <= t) ? v[cc] : -INFINITY;
        unsigned u = __float_as_uint(x);
        su[c * 4 + cc] = (u & 0x80000000u) ? ~u : (u | 0x80000000u);
      }
    } else {
#pragma unroll
      for (int cc = 0; cc < 4; cc++) su[c * 4 + cc] = 0x007FFFFFu;  // map(-inf)
    }
  }
  // radix search for max lo with count(su >= lo) >= 64; early-exit min-refine at cnt==64
  unsigned lo = 0;
#pragma unroll 1
  for (int bit = 31; bit >= 0; bit--) {
    unsigned cand = lo | (1u << bit);
    int cnt = 0;
#pragma unroll
    for (int c = 0; c < 8; c++)
      if (c * 256 < stride)
#pragma unroll
        for (int q = 0; q < 4; q++)
          cnt += (int)__popcll(__ballot(su[c * 4 + q] >= cand));
    if (cnt >= 64) {
      lo = cand;
      if (cnt == 64) {
        unsigned mn = 0xFFFFFFFFu;
#pragma unroll
        for (int c = 0; c < 8; c++)
          if (c * 256 < stride)
#pragma unroll
            for (int q = 0; q < 4; q++) { unsigned x = (su[c * 4 + q] >= cand) ? su[c * 4 + q] : 0xFFFFFFFFu; mn = mn < x ? mn : x; }
#pragma unroll
        for (int o = 32; o; o >>= 1) { unsigned x = (unsigned)__shfl_xor((int)mn, o); mn = mn < x ? mn : x; }
        lo = mn;
        break;
      }
    }
  }
  unsigned mx = 0;
#pragma unroll
  for (int c = 0; c < 8; c++)
    if (c * 256 < stride)
#pragma unroll
      for (int q = 0; q < 4; q++) mx = mx > su[c * 4 + q] ? mx : su[c * 4 + q];
#pragma unroll
  for (int o = 32; o; o >>= 1) { unsigned x = (unsigned)__shfl_xor((int)mx, o); mx = mx > x ? mx : x; }
  float m = su2f(mx);
  float sum = 0.f;
#pragma unroll
  for (int c = 0; c < 8; c++)
    if (c * 256 < stride)
#pragma unroll
      for (int q = 0; q < 4; q++) {
        float v = su2f(su[c * 4 + q]);
        float wv = (su[c * 4 + q] >= lo) ? __expf(v - m) : 0.f;  // exp(-inf)=0
        su[c * 4 + q] = __float_as_uint(wv);
        sum += wv;
      }
  sum = wave_sum_f(sum);
  float inv = 1.f / sum;
  unsigned short* prow = (unsigned short*)row;
#pragma unroll
  for (int c = 0; c < 8; c++) {
    if (c * 256 < stride) {
      int j0 = c * 256 + lane * 4;
      if (j0 < stride) {
        u16x4 pk;
#pragma unroll
        for (int cc = 0; cc < 4; cc++) pk[cc] = f2bf(__uint_as_float(su[c * 4 + cc]) * inv);
        *(u16x4*)(prow + j0) = pk;
      }
    }
  }
}

// ---------- Y = P @ V^T (dense causal MFMA), epilogue splits Y to bf16 hi/lo ----------
__global__ __launch_bounds__(512) void pv_k(const float* __restrict__ S,
    const unsigned short* __restrict__ Vt,
    unsigned short* __restrict__ Yhi, unsigned short* __restrict__ Ylo, int bh0) {
  __shared__ unsigned short Ps[128][136];
  __shared__ unsigned short Vs[64][136];
  const int rt = blockIdx.x, bh = bh0 + blockIdx.y, b = bh >> 3, h = bh & 7;
  const int tid = threadIdx.x, w = tid >> 6, lane = tid & 63, e = lane >> 4, lr = lane & 15;
  const int stride = (rt + 1) * 128;
  const float* Srow0 = S + (size_t)(bh - bh0) * TRI_FLOATS + (size_t)tri_i(rt) * 16384;
  f32x4 acc[4] = {};
  for (int kt = 0; kt <= rt; kt++) {
#pragma unroll
    for (int p = 0; p < 4; p++) {
      int idx = tid + p * 512, row = idx >> 4, seg = idx & 15;
      const unsigned short* src = (const unsigned short*)(Srow0 + (size_t)row * stride) + kt * 128 + seg * 8;
      *(u16x8*)&Ps[row][seg * 8] = *(const u16x8*)src;
    }
#pragma unroll
    for (int p = 0; p < 2; p++) {
      int idx = tid + p * 512, d = idx >> 4, seg = idx & 15;
      *(u16x8*)&Vs[d][seg * 8] = *(const u16x8*)&Vt[((size_t)(bh * 64 + d)) * Tc + kt * 128 + seg * 8];
    }
    __syncthreads();
#pragma unroll
    for (int ks = 0; ks < 4; ks++) {
      s16x8 a = *(const s16x8*)&Ps[w * 16 + lr][ks * 32 + e * 8];
#pragma unroll
      for (int tj = 0; tj < 4; tj++) {
        s16x8 bb = *(const s16x8*)&Vs[tj * 16 + lr][ks * 32 + e * 8];
        acc[tj] = __builtin_amdgcn_mfma_f32_16x16x32_bf16(a, bb, acc[tj], 0, 0, 0);
      }
    }
    __syncthreads();
  }
#pragma unroll
  for (int tj = 0; tj < 4; tj++)
#pragma unroll
    for (int r = 0; r < 4; r++) {
      int row = rt * 128 + w * 16 + e * 4 + r;
      size_t g = ((size_t)(b * Tc + row)) * Cch + h * 64 + tj * 16 + lr;
      float y = acc[tj][r];
      unsigned short hh = f2bf(y);
      Yhi[g] = hh;
      Ylo[g] = f2bf(y - bf2f(hh));
    }
}

extern "C" void kernel_launch(void* const* d_in, const int* in_sizes, int n_in,
                              void* d_out, int out_size, void* d_ws, size_t ws_size,
                              hipStream_t stream) {
  const float* q  = (const float*)d_in[0];
  // d_in[1] = tgt_mask: pure causal tril, handled analytically
  const float* Wq = (const float*)d_in[2];
  const float* bq = (const float*)d_in[3];
  const float* Wk = (const float*)d_in[4];
  const float* bk = (const float*)d_in[5];
  const float* Wv = (const float*)d_in[6];
  const float* bv = (const float*)d_in[7];
  const float* Wp = (const float*)d_in[8];
  const float* bp = (const float*)d_in[9];
  float* out = (float*)d_out;
  char* ws = (char*)d_ws;
  constexpr size_t MB = 1u << 20;

  unsigned short* qhi = (unsigned short*)(ws + 0 * MB);   // 4 MB (later Yhi)
  unsigned short* qlo = (unsigned short*)(ws + 4 * MB);   // 4 MB (later Ylo)
  unsigned short* Qp  = (unsigned short*)(ws + 8 * MB);   // 4 MB
  unsigned short* Kp  = (unsigned short*)(ws + 12 * MB);  // 4 MB
  unsigned short* Vt  = (unsigned short*)(ws + 16 * MB);  // 4 MB
  unsigned short* wsp = (unsigned short*)(ws + 20 * MB);  // 8 x 512 KB weight splits
  float* Sb = (float*)(ws + 24 * MB);                     // S/P region (chunked)
  float* Vf = (float*)(ws + 24 * MB);                     // overlays S (consumed first)
  unsigned short* Yhi = qhi;
  unsigned short* Ylo = qlo;
  auto WT = [&](int i) { return wsp + (size_t)i * 262144; };

  int nbh = NBH;
  while (nbh > 1 && 24 * MB + TRI_FLOATS * 4 * (size_t)nbh > ws_size) nbh >>= 1;

  split_k<<<(BT * Cch / 8 + 255) / 256, 256, 0, stream>>>(q, qhi, qlo, BT * Cch / 8);
  dim3 g8(8, 8);
  splitT_k<<<g8, 256, 0, stream>>>(Wq, WT(0), WT(1));
  splitT_k<<<g8, 256, 0, stream>>>(Wk, WT(2), WT(3));
  splitT_k<<<g8, 256, 0, stream>>>(Wv, WT(4), WT(5));
  splitT_k<<<g8, 256, 0, stream>>>(Wp, WT(6), WT(7));

  dim3 gp(Cch / 64, BT / 64);  // (8, 64)
  gemm3_k<1><<<gp, 256, 0, stream>>>(qhi, qlo, WT(0), WT(1), bq, Qp);
  gemm3_k<1><<<gp, 256, 0, stream>>>(qhi, qlo, WT(2), WT(3), bk, Kp);
  gemm3_k<0><<<gp, 256, 0, stream>>>(qhi, qlo, WT(4), WT(5), bv, Vf);
  vnormt_k<<<dim3(BT / 64, Hc), 256, 0, stream>>>(Vf, Vt);

  for (int c = 0; c < NBH / nbh; c++) {
    int bh0 = c * nbh;
    sqk_k<<<dim3(NTRI, nbh), 512, 0, stream>>>(Qp, Kp, Sb, bh0);
    sel_k<<<nbh * 256, 512, 0, stream>>>(Sb);
    pv_k<<<dim3(NRT, nbh), 512, 0, stream>>>(Sb, Vt, Yhi, Ylo, bh0);
  }

  gemm3_k<0><<<gp, 256, 0, stream>>>(Yhi, Ylo, WT(6), WT(7), bp, out);
}

// Round 9
// 209.375 us; speedup vs baseline: 1.3399x; 1.0814x over previous
//
#include <hip/hip_runtime.h>
#include <cstdint>
#include <math.h>

static constexpr int Bc = 2, Tc = 2048, Cch = 512, Hc = 8;
static constexpr int BT = Bc * Tc;          // 4096
static constexpr int NBH = Bc * Hc;         // 16
static constexpr int NRT = Tc / 128;        // 16 row-tiles per (b,h)
static constexpr int NTRI = NRT * (NRT + 1) / 2;  // 136 causal blocks
static constexpr size_t TRI_FLOATS = (size_t)NTRI * 16384;  // f32 per (b,h)

typedef float f32x4 __attribute__((ext_vector_type(4)));
typedef short s16x8 __attribute__((ext_vector_type(8)));
typedef unsigned short u16x8 __attribute__((ext_vector_type(8)));
typedef unsigned short u16x4 __attribute__((ext_vector_type(4)));

__device__ __host__ inline constexpr int tri_i(int r) { return r * (r + 1) / 2; }

__device__ inline float wave_sum_f(float x) {
#pragma unroll
  for (int o = 32; o; o >>= 1) x += __shfl_xor(x, o);
  return x;
}
__device__ inline unsigned short f2bf(float x) {  // RNE f32->bf16 (finite)
  unsigned u = __float_as_uint(x);
  return (unsigned short)((u + 0x7FFFu + ((u >> 16) & 1u)) >> 16);
}
__device__ inline float bf2f(unsigned short h) { return __uint_as_float(((unsigned)h) << 16); }
__device__ inline float su2f(unsigned s) {  // inverse order-preserving map
  unsigned u = (s & 0x80000000u) ? (s ^ 0x80000000u) : ~s;
  return __uint_as_float(u);
}

// ---------- split f32 -> bf16 hi/lo ----------
__global__ __launch_bounds__(256) void split_k(const float* __restrict__ X,
    unsigned short* __restrict__ hi, unsigned short* __restrict__ lo, int n8) {
  int i = blockIdx.x * 256 + threadIdx.x;
  if (i >= n8) return;
  const f32x4* p = (const f32x4*)X + (size_t)i * 2;
  f32x4 a = p[0], b = p[1];
  float v[8] = {a[0], a[1], a[2], a[3], b[0], b[1], b[2], b[3]};
  u16x8 h, l;
#pragma unroll
  for (int c = 0; c < 8; c++) {
    unsigned short hh = f2bf(v[c]);
    h[c] = hh;
    l[c] = f2bf(v[c] - bf2f(hh));
  }
  *(u16x8*)(hi + (size_t)i * 8) = h;
  *(u16x8*)(lo + (size_t)i * 8) = l;
}

// ---------- split + transpose all 4 weights: W[k][n] f32 -> WT[n][k] bf16 hi/lo ----------
__global__ __launch_bounds__(256) void splitT4_k(const float* __restrict__ Wq,
    const float* __restrict__ Wk, const float* __restrict__ Wv,
    const float* __restrict__ Wp, unsigned short* __restrict__ wsp) {
  const int z = blockIdx.z;
  const float* W = (z == 0) ? Wq : (z == 1) ? Wk : (z == 2) ? Wv : Wp;
  unsigned short* hiT = wsp + (size_t)z * 524288;
  unsigned short* loT = hiT + 262144;
  __shared__ float t[64][65];
  const int tid = threadIdx.x;
  const int k0 = blockIdx.x * 64, n0 = blockIdx.y * 64;
#pragma unroll
  for (int p = 0; p < 4; p++) {
    int idx = tid + p * 256, kk = idx >> 4, n4 = idx & 15;
    f32x4 v = *(const f32x4*)&W[(size_t)(k0 + kk) * Cch + n0 + n4 * 4];
    t[kk][n4 * 4 + 0] = v[0]; t[kk][n4 * 4 + 1] = v[1];
    t[kk][n4 * 4 + 2] = v[2]; t[kk][n4 * 4 + 3] = v[3];
  }
  __syncthreads();
  {
    int n = tid >> 2, ks = tid & 3;
    u16x8 h0, h1, l0, l1;
#pragma unroll
    for (int kk = 0; kk < 8; kk++) {
      float x = t[ks * 16 + kk][n];
      unsigned short hh = f2bf(x);
      h0[kk] = hh; l0[kk] = f2bf(x - bf2f(hh));
      float y = t[ks * 16 + 8 + kk][n];
      unsigned short hy = f2bf(y);
      h1[kk] = hy; l1[kk] = f2bf(y - bf2f(hy));
    }
    size_t base = (size_t)(n0 + n) * Cch + k0 + ks * 16;
    *(u16x8*)(hiT + base) = h0; *(u16x8*)(hiT + base + 8) = h1;
    *(u16x8*)(loT + base) = l0; *(u16x8*)(loT + base + 8) = l1;
  }
}

// ---------- bf16x3 MFMA GEMM (single weight), used for the final projection ----------
template <int BF16OUT>
__global__ __launch_bounds__(256) void gemm3_k(
    const unsigned short* __restrict__ Ahi, const unsigned short* __restrict__ Alo,
    const unsigned short* __restrict__ Bhi, const unsigned short* __restrict__ Blo,
    const float* __restrict__ bias, void* __restrict__ Out) {
  __shared__ unsigned short Ah[2][64][72];
  __shared__ unsigned short Bs[2][64][72];
  const int tid = threadIdx.x;
  const int w = tid >> 6, lane = tid & 63, e = lane >> 4, lr = lane & 15;
  const int wr = w >> 1, wc = w & 1;
  const int brow = blockIdx.y * 64, bcol = blockIdx.x * 64;
  f32x4 acc[2][2] = {};
  for (int k0 = 0; k0 < Cch; k0 += 64) {
#pragma unroll
    for (int p = 0; p < 2; p++) {
      int idx = tid + p * 256, row = idx >> 3, seg = idx & 7;
      *(u16x8*)&Ah[0][row][seg * 8] = *(const u16x8*)&Ahi[(size_t)(brow + row) * Cch + k0 + seg * 8];
      *(u16x8*)&Ah[1][row][seg * 8] = *(const u16x8*)&Alo[(size_t)(brow + row) * Cch + k0 + seg * 8];
      *(u16x8*)&Bs[0][row][seg * 8] = *(const u16x8*)&Bhi[(size_t)(bcol + row) * Cch + k0 + seg * 8];
      *(u16x8*)&Bs[1][row][seg * 8] = *(const u16x8*)&Blo[(size_t)(bcol + row) * Cch + k0 + seg * 8];
    }
    __syncthreads();
#pragma unroll
    for (int ks = 0; ks < 2; ks++) {
      s16x8 ah[2], al[2], bh[2], bl[2];
#pragma unroll
      for (int ti = 0; ti < 2; ti++) {
        ah[ti] = *(const s16x8*)&Ah[0][wr * 32 + ti * 16 + lr][ks * 32 + e * 8];
        al[ti] = *(const s16x8*)&Ah[1][wr * 32 + ti * 16 + lr][ks * 32 + e * 8];
      }
#pragma unroll
      for (int tj = 0; tj < 2; tj++) {
        bh[tj] = *(const s16x8*)&Bs[0][wc * 32 + tj * 16 + lr][ks * 32 + e * 8];
        bl[tj] = *(const s16x8*)&Bs[1][wc * 32 + tj * 16 + lr][ks * 32 + e * 8];
      }
#pragma unroll
      for (int ti = 0; ti < 2; ti++)
#pragma unroll
        for (int tj = 0; tj < 2; tj++) {
          acc[ti][tj] = __builtin_amdgcn_mfma_f32_16x16x32_bf16(ah[ti], bh[tj], acc[ti][tj], 0, 0, 0);
          acc[ti][tj] = __builtin_amdgcn_mfma_f32_16x16x32_bf16(ah[ti], bl[tj], acc[ti][tj], 0, 0, 0);
          acc[ti][tj] = __builtin_amdgcn_mfma_f32_16x16x32_bf16(al[ti], bh[tj], acc[ti][tj], 0, 0, 0);
        }
    }
    __syncthreads();
  }
#pragma unroll
  for (int ti = 0; ti < 2; ti++)
#pragma unroll
    for (int tj = 0; tj < 2; tj++) {
      int col = bcol + wc * 32 + tj * 16 + lr;
      float bi = bias[col];
#pragma unroll
      for (int r = 0; r < 4; r++) {
        int row = brow + wr * 32 + ti * 16 + e * 4 + r;
        float v = acc[ti][tj][r] + bi;
        if (BF16OUT) ((unsigned short*)Out)[(size_t)row * Cch + col] = f2bf(v);
        else         ((float*)Out)[(size_t)row * Cch + col] = v;
      }
    }
}

// ---------- merged Q/K/V projection: gridDim.z selects weight/bias/output ----------
__global__ __launch_bounds__(256) void gemm3_qkv_k(
    const unsigned short* __restrict__ Ahi, const unsigned short* __restrict__ Alo,
    const unsigned short* __restrict__ wsp,
    const float* __restrict__ bq, const float* __restrict__ bk, const float* __restrict__ bv,
    unsigned short* __restrict__ Qp, unsigned short* __restrict__ Kp, float* __restrict__ Vf) {
  const int z = blockIdx.z;
  const unsigned short* Bhi = wsp + (size_t)z * 524288;
  const unsigned short* Blo = Bhi + 262144;
  const float* bias = (z == 0) ? bq : (z == 1) ? bk : bv;
  __shared__ unsigned short Ah[2][64][72];
  __shared__ unsigned short Bs[2][64][72];
  const int tid = threadIdx.x;
  const int w = tid >> 6, lane = tid & 63, e = lane >> 4, lr = lane & 15;
  const int wr = w >> 1, wc = w & 1;
  const int brow = blockIdx.y * 64, bcol = blockIdx.x * 64;
  f32x4 acc[2][2] = {};
  for (int k0 = 0; k0 < Cch; k0 += 64) {
#pragma unroll
    for (int p = 0; p < 2; p++) {
      int idx = tid + p * 256, row = idx >> 3, seg = idx & 7;
      *(u16x8*)&Ah[0][row][seg * 8] = *(const u16x8*)&Ahi[(size_t)(brow + row) * Cch + k0 + seg * 8];
      *(u16x8*)&Ah[1][row][seg * 8] = *(const u16x8*)&Alo[(size_t)(brow + row) * Cch + k0 + seg * 8];
      *(u16x8*)&Bs[0][row][seg * 8] = *(const u16x8*)&Bhi[(size_t)(bcol + row) * Cch + k0 + seg * 8];
      *(u16x8*)&Bs[1][row][seg * 8] = *(const u16x8*)&Blo[(size_t)(bcol + row) * Cch + k0 + seg * 8];
    }
    __syncthreads();
#pragma unroll
    for (int ks = 0; ks < 2; ks++) {
      s16x8 ah[2], al[2], bh[2], bl[2];
#pragma unroll
      for (int ti = 0; ti < 2; ti++) {
        ah[ti] = *(const s16x8*)&Ah[0][wr * 32 + ti * 16 + lr][ks * 32 + e * 8];
        al[ti] = *(const s16x8*)&Ah[1][wr * 32 + ti * 16 + lr][ks * 32 + e * 8];
      }
#pragma unroll
      for (int tj = 0; tj < 2; tj++) {
        bh[tj] = *(const s16x8*)&Bs[0][wc * 32 + tj * 16 + lr][ks * 32 + e * 8];
        bl[tj] = *(const s16x8*)&Bs[1][wc * 32 + tj * 16 + lr][ks * 32 + e * 8];
      }
#pragma unroll
      for (int ti = 0; ti < 2; ti++)
#pragma unroll
        for (int tj = 0; tj < 2; tj++) {
          acc[ti][tj] = __builtin_amdgcn_mfma_f32_16x16x32_bf16(ah[ti], bh[tj], acc[ti][tj], 0, 0, 0);
          acc[ti][tj] = __builtin_amdgcn_mfma_f32_16x16x32_bf16(ah[ti], bl[tj], acc[ti][tj], 0, 0, 0);
          acc[ti][tj] = __builtin_amdgcn_mfma_f32_16x16x32_bf16(al[ti], bh[tj], acc[ti][tj], 0, 0, 0);
        }
    }
    __syncthreads();
  }
#pragma unroll
  for (int ti = 0; ti < 2; ti++)
#pragma unroll
    for (int tj = 0; tj < 2; tj++) {
      int col = bcol + wc * 32 + tj * 16 + lr;
      float bi = bias[col];
#pragma unroll
      for (int r = 0; r < 4; r++) {
        int row = brow + wr * 32 + ti * 16 + e * 4 + r;
        float v = acc[ti][tj][r] + bi;
        size_t g = (size_t)row * Cch + col;
        if (z == 0) Qp[g] = f2bf(v);
        else if (z == 1) Kp[g] = f2bf(v);
        else Vf[g] = v;
      }
    }
}

// ---------- V normalize + transpose via LDS: Vf[token][C] f32 -> Vt[bh*64+d][t] bf16 ----------
__global__ __launch_bounds__(256) void vnormt_k(const float* __restrict__ Vf,
                                                unsigned short* __restrict__ Vt) {
  __shared__ unsigned short T[64][72];  // [d][token] bf16
  const int tid = threadIdx.x;
  const int t0 = blockIdx.x * 64;
  const int h = blockIdx.y;
  const int tok = tid >> 2;
  const int q = tid & 3;
  const float* src = Vf + (size_t)(t0 + tok) * Cch + h * 64 + q * 16;
  f32x4 v[4];
  float ss = 0.f;
#pragma unroll
  for (int i = 0; i < 4; i++) {
    v[i] = *(const f32x4*)(src + i * 4);
#pragma unroll
    for (int c = 0; c < 4; c++) ss += v[i][c] * v[i][c];
  }
  ss += __shfl_xor(ss, 1);
  ss += __shfl_xor(ss, 2);
  float inv = 1.0f / fmaxf(sqrtf(ss), 1e-12f);
#pragma unroll
  for (int i = 0; i < 4; i++)
#pragma unroll
    for (int c = 0; c < 4; c++)
      T[q * 16 + i * 4 + c][tok] = f2bf(v[i][c] * inv);
  __syncthreads();
  const int d = tid >> 2, s2 = (tid & 3) * 2;
  const int b = t0 >> 11;
  size_t base = ((size_t)((b * Hc + h) * 64 + d)) * Tc + (t0 & 2047);
  *(u16x8*)(Vt + base + s2 * 8)     = *(const u16x8*)&T[d][s2 * 8];
  *(u16x8*)(Vt + base + s2 * 8 + 8) = *(const u16x8*)&T[d][s2 * 8 + 8];
}

// ---------- S = (Q K^T)/8 into causal-compact triangular storage ----------
__global__ __launch_bounds__(512) void sqk_k(const unsigned short* __restrict__ Qp,
    const unsigned short* __restrict__ Kp, float* __restrict__ S, int bh0) {
  __shared__ unsigned short Qs[128][72], Ks[128][72];
  int rt, ct;
  {
    int i = blockIdx.x;
    int r = (int)((sqrtf(8.f * i + 1.f) - 1.f) * 0.5f);
    while ((r + 1) * (r + 2) / 2 <= i) r++;
    while (r * (r + 1) / 2 > i) r--;
    rt = r; ct = i - r * (r + 1) / 2;
  }
  const int bh = bh0 + blockIdx.y, b = bh >> 3, h = bh & 7;
  const int tid = threadIdx.x, w = tid >> 6, lane = tid & 63, e = lane >> 4, lr = lane & 15;
#pragma unroll
  for (int p = 0; p < 2; p++) {
    int idx = tid + p * 512, row = idx >> 3, seg = idx & 7;
    *(u16x8*)&Qs[row][seg * 8] = *(const u16x8*)&Qp[((size_t)(b * Tc + rt * 128 + row)) * Cch + h * 64 + seg * 8];
    *(u16x8*)&Ks[row][seg * 8] = *(const u16x8*)&Kp[((size_t)(b * Tc + ct * 128 + row)) * Cch + h * 64 + seg * 8];
  }
  __syncthreads();
  f32x4 acc[8] = {};
  s16x8 a[2];
#pragma unroll
  for (int ks = 0; ks < 2; ks++) a[ks] = *(const s16x8*)&Qs[w * 16 + lr][ks * 32 + e * 8];
#pragma unroll
  for (int tj = 0; tj < 8; tj++) {
#pragma unroll
    for (int ks = 0; ks < 2; ks++) {
      s16x8 bb = *(const s16x8*)&Ks[tj * 16 + lr][ks * 32 + e * 8];
      acc[tj] = __builtin_amdgcn_mfma_f32_16x16x32_bf16(a[ks], bb, acc[tj], 0, 0, 0);
    }
  }
  float* Srow0 = S + (size_t)(bh - bh0) * TRI_FLOATS + (size_t)tri_i(rt) * 16384;
  const int stride = (rt + 1) * 128;
#pragma unroll
  for (int tj = 0; tj < 8; tj++)
#pragma unroll
    for (int r = 0; r < 4; r++) {
      int row = w * 16 + e * 4 + r;
      Srow0[(size_t)row * stride + ct * 128 + tj * 16 + lr] = acc[tj][r] * 0.125f;
    }
}

// ---------- exact top-64 + softmax; writes normalized P bf16 in-place ----------
// chunk-guarded; LONGEST-FIRST block order (LPT) to kill the occupancy tail
__global__ __launch_bounds__(512, 4) void sel_k(float* __restrict__ S) {
  int bidr = (int)gridDim.x - 1 - (int)blockIdx.x;   // long rows dispatch first
  int wid = bidr * 8 + (threadIdx.x >> 6);
  int lane = threadIdx.x & 63;
  int bhl = wid >> 11, t = wid & 2047;
  int rt = t >> 7, lrow = t & 127;
  int stride = (rt + 1) * 128;
  float* row = S + (size_t)bhl * TRI_FLOATS + (size_t)tri_i(rt) * 16384 + (size_t)lrow * stride;
  unsigned su[32];
#pragma unroll
  for (int c = 0; c < 8; c++) {
    if (c * 256 < stride) {
      int j0 = c * 256 + lane * 4;
      f32x4 v;
      if (j0 < stride) v = *(const f32x4*)(row + j0);
      else { v[0] = v[1] = v[2] = v[3] = -INFINITY; }
#pragma unroll
      for (int cc = 0; cc < 4; cc++) {
        float x = (j0 + cc <= t) ? v[cc] : -INFINITY;
        unsigned u = __float_as_uint(x);
        su[c * 4 + cc] = (u & 0x80000000u) ? ~u : (u | 0x80000000u);
      }
    } else {
#pragma unroll
      for (int cc = 0; cc < 4; cc++) su[c * 4 + cc] = 0x007FFFFFu;  // map(-inf)
    }
  }
  // radix search for max lo with count(su >= lo) >= 64; early-exit min-refine at cnt==64
  unsigned lo = 0;
#pragma unroll 1
  for (int bit = 31; bit >= 0; bit--) {
    unsigned cand = lo | (1u << bit);
    int cnt = 0;
#pragma unroll
    for (int c = 0; c < 8; c++)
      if (c * 256 < stride)
#pragma unroll
        for (int q = 0; q < 4; q++)
          cnt += (int)__popcll(__ballot(su[c * 4 + q] >= cand));
    if (cnt >= 64) {
      lo = cand;
      if (cnt == 64) {
        unsigned mn = 0xFFFFFFFFu;
#pragma unroll
        for (int c = 0; c < 8; c++)
          if (c * 256 < stride)
#pragma unroll
            for (int q = 0; q < 4; q++) { unsigned x = (su[c * 4 + q] >= cand) ? su[c * 4 + q] : 0xFFFFFFFFu; mn = mn < x ? mn : x; }
#pragma unroll
        for (int o = 32; o; o >>= 1) { unsigned x = (unsigned)__shfl_xor((int)mn, o); mn = mn < x ? mn : x; }
        lo = mn;
        break;
      }
    }
  }
  unsigned mx = 0;
#pragma unroll
  for (int c = 0; c < 8; c++)
    if (c * 256 < stride)
#pragma unroll
      for (int q = 0; q < 4; q++) mx = mx > su[c * 4 + q] ? mx : su[c * 4 + q];
#pragma unroll
  for (int o = 32; o; o >>= 1) { unsigned x = (unsigned)__shfl_xor((int)mx, o); mx = mx > x ? mx : x; }
  float m = su2f(mx);
  float sum = 0.f;
#pragma unroll
  for (int c = 0; c < 8; c++)
    if (c * 256 < stride)
#pragma unroll
      for (int q = 0; q < 4; q++) {
        float v = su2f(su[c * 4 + q]);
        float wv = (su[c * 4 + q] >= lo) ? __expf(v - m) : 0.f;  // exp(-inf)=0
        su[c * 4 + q] = __float_as_uint(wv);
        sum += wv;
      }
  sum = wave_sum_f(sum);
  float inv = 1.f / sum;
  unsigned short* prow = (unsigned short*)row;
#pragma unroll
  for (int c = 0; c < 8; c++) {
    if (c * 256 < stride) {
      int j0 = c * 256 + lane * 4;
      if (j0 < stride) {
        u16x4 pk;
#pragma unroll
        for (int cc = 0; cc < 4; cc++) pk[cc] = f2bf(__uint_as_float(su[c * 4 + cc]) * inv);
        *(u16x4*)(prow + j0) = pk;
      }
    }
  }
}

// ---------- Y = P @ V^T (dense causal MFMA), LONGEST-FIRST rt order ----------
__global__ __launch_bounds__(512) void pv_k(const float* __restrict__ S,
    const unsigned short* __restrict__ Vt,
    unsigned short* __restrict__ Yhi, unsigned short* __restrict__ Ylo, int bh0) {
  __shared__ unsigned short Ps[128][136];
  __shared__ unsigned short Vs[64][136];
  const int rt = (int)gridDim.x - 1 - (int)blockIdx.x;  // big rt first
  const int bh = bh0 + blockIdx.y, b = bh >> 3, h = bh & 7;
  const int tid = threadIdx.x, w = tid >> 6, lane = tid & 63, e = lane >> 4, lr = lane & 15;
  const int stride = (rt + 1) * 128;
  const float* Srow0 = S + (size_t)(bh - bh0) * TRI_FLOATS + (size_t)tri_i(rt) * 16384;
  f32x4 acc[4] = {};
  for (int kt = 0; kt <= rt; kt++) {
#pragma unroll
    for (int p = 0; p < 4; p++) {
      int idx = tid + p * 512, row = idx >> 4, seg = idx & 15;
      const unsigned short* src = (const unsigned short*)(Srow0 + (size_t)row * stride) + kt * 128 + seg * 8;
      *(u16x8*)&Ps[row][seg * 8] = *(const u16x8*)src;
    }
#pragma unroll
    for (int p = 0; p < 2; p++) {
      int idx = tid + p * 512, d = idx >> 4, seg = idx & 15;
      *(u16x8*)&Vs[d][seg * 8] = *(const u16x8*)&Vt[((size_t)(bh * 64 + d)) * Tc + kt * 128 + seg * 8];
    }
    __syncthreads();
#pragma unroll
    for (int ks = 0; ks < 4; ks++) {
      s16x8 a = *(const s16x8*)&Ps[w * 16 + lr][ks * 32 + e * 8];
#pragma unroll
      for (int tj = 0; tj < 4; tj++) {
        s16x8 bb = *(const s16x8*)&Vs[tj * 16 + lr][ks * 32 + e * 8];
        acc[tj] = __builtin_amdgcn_mfma_f32_16x16x32_bf16(a, bb, acc[tj], 0, 0, 0);
      }
    }
    __syncthreads();
  }
#pragma unroll
  for (int tj = 0; tj < 4; tj++)
#pragma unroll
    for (int r = 0; r < 4; r++) {
      int row = rt * 128 + w * 16 + e * 4 + r;
      size_t g = ((size_t)(b * Tc + row)) * Cch + h * 64 + tj * 16 + lr;
      float y = acc[tj][r];
      unsigned short hh = f2bf(y);
      Yhi[g] = hh;
      Ylo[g] = f2bf(y - bf2f(hh));
    }
}

extern "C" void kernel_launch(void* const* d_in, const int* in_sizes, int n_in,
                              void* d_out, int out_size, void* d_ws, size_t ws_size,
                              hipStream_t stream) {
  const float* q  = (const float*)d_in[0];
  // d_in[1] = tgt_mask: pure causal tril, handled analytically
  const float* Wq = (const float*)d_in[2];
  const float* bq = (const float*)d_in[3];
  const float* Wk = (const float*)d_in[4];
  const float* bk = (const float*)d_in[5];
  const float* Wv = (const float*)d_in[6];
  const float* bv = (const float*)d_in[7];
  const float* Wp = (const float*)d_in[8];
  const float* bp = (const float*)d_in[9];
  float* out = (float*)d_out;
  char* ws = (char*)d_ws;
  constexpr size_t MB = 1u << 20;

  unsigned short* qhi = (unsigned short*)(ws + 0 * MB);   // 4 MB (later Yhi)
  unsigned short* qlo = (unsigned short*)(ws + 4 * MB);   // 4 MB (later Ylo)
  unsigned short* Qp  = (unsigned short*)(ws + 8 * MB);   // 4 MB
  unsigned short* Kp  = (unsigned short*)(ws + 12 * MB);  // 4 MB
  unsigned short* Vt  = (unsigned short*)(ws + 16 * MB);  // 4 MB
  unsigned short* wsp = (unsigned short*)(ws + 20 * MB);  // 8 x 512 KB weight splits
  float* Sb = (float*)(ws + 24 * MB);                     // S/P region (chunked)
  float* Vf = (float*)(ws + 24 * MB);                     // overlays S (consumed first)
  unsigned short* Yhi = qhi;
  unsigned short* Ylo = qlo;

  int nbh = NBH;
  while (nbh > 1 && 24 * MB + TRI_FLOATS * 4 * (size_t)nbh > ws_size) nbh >>= 1;

  split_k<<<(BT * Cch / 8 + 255) / 256, 256, 0, stream>>>(q, qhi, qlo, BT * Cch / 8);
  splitT4_k<<<dim3(8, 8, 4), 256, 0, stream>>>(Wq, Wk, Wv, Wp, wsp);

  gemm3_qkv_k<<<dim3(Cch / 64, BT / 64, 3), 256, 0, stream>>>(
      qhi, qlo, wsp, bq, bk, bv, Qp, Kp, Vf);
  vnormt_k<<<dim3(BT / 64, Hc), 256, 0, stream>>>(Vf, Vt);

  for (int c = 0; c < NBH / nbh; c++) {
    int bh0 = c * nbh;
    sqk_k<<<dim3(NTRI, nbh), 512, 0, stream>>>(Qp, Kp, Sb, bh0);
    sel_k<<<nbh * 256, 512, 0, stream>>>(Sb);
    pv_k<<<dim3(NRT, nbh), 512, 0, stream>>>(Sb, Vt, Yhi, Ylo, bh0);
  }

  gemm3_k<0><<<dim3(Cch / 64, BT / 64), 256, 0, stream>>>(
      Yhi, qlo /*Ylo*/, wsp + (size_t)6 * 262144, wsp + (size_t)7 * 262144, bp, out);
}